// Round 10
// baseline (23992.874 us; speedup 1.0000x reference)
//
#include <hip/hip_runtime.h>
#include <math.h>

// Problem constants
#define DD 256            // latent dim
#define KK 8192           // codebook size
#define NN 16384          // rows
#define NBLOCKS 512       // gather/partial grid (verified 32-row geometry)
#define RSTRIDE 260       // rowsumsq staging stride (unchanged, verified)
#define EPS 2e-3f         // candidate threshold: 6.6x the worst-row approx-error bound
#define CANDCAP 64        // per-row candidate cap (expected ~14; overflow -> full scan)

// Output layout (all float32, concatenated in reference return order)
#define OUT_IDS   0
#define OUT_Q     16384
#define OUT_ST    4210688          // 16384 + 4194304
#define OUT_COMMIT 8404992
#define OUT_CBL    8404993
#define OUT_PERP   8404994

// MFMA fragment types (per guide §3: verified on gfx950)
using bf16x8 = __attribute__((ext_vector_type(8))) short;
using f32x4  = __attribute__((ext_vector_type(4))) float;

// fp32 -> bf16 RNE (finite inputs; bit pattern in ushort)
__device__ __forceinline__ unsigned short f2bf(float f) {
    unsigned u = __float_as_uint(f);
    return (unsigned short)((u + 0x7FFFu + ((u >> 16) & 1u)) >> 16);
}

// ---------------------------------------------------------------------------
// numpy pairwise-sum replica for sum of squares (verified bit-exact)
// ---------------------------------------------------------------------------
__device__ __forceinline__ float np_block128_sumsq(const float* p) {
    #pragma clang fp contract(off)
    float r0 = p[0] * p[0], r1 = p[1] * p[1], r2 = p[2] * p[2], r3 = p[3] * p[3];
    float r4 = p[4] * p[4], r5 = p[5] * p[5], r6 = p[6] * p[6], r7 = p[7] * p[7];
    for (int i = 8; i < 128; i += 8) {
        r0 = r0 + p[i + 0] * p[i + 0];
        r1 = r1 + p[i + 1] * p[i + 1];
        r2 = r2 + p[i + 2] * p[i + 2];
        r3 = r3 + p[i + 3] * p[i + 3];
        r4 = r4 + p[i + 4] * p[i + 4];
        r5 = r5 + p[i + 5] * p[i + 5];
        r6 = r6 + p[i + 6] * p[i + 6];
        r7 = r7 + p[i + 7] * p[i + 7];
    }
    return ((r0 + r1) + (r2 + r3)) + ((r4 + r5) + (r6 + r7));
}

__device__ __forceinline__ float np_pairwise256_sumsq(const float* a) {
    #pragma clang fp contract(off)
    float s0 = np_block128_sumsq(a);
    float s1 = np_block128_sumsq(a + 128);
    return s0 + s1;
}

// ---------------------------------------------------------------------------
// Kernel 1: per-row sum of squares, numpy-pairwise-exact (unchanged, verified)
// ---------------------------------------------------------------------------
__global__ __launch_bounds__(256) void rowsumsq(const float* __restrict__ A,
                                                float* __restrict__ out) {
    __shared__ __align__(16) float sA[64][RSTRIDE];
    const int tid = threadIdx.x;
    const int base = blockIdx.x * 64;
    #pragma unroll
    for (int i = 0; i < 16; ++i) {
        int g = i * 256 + tid;
        int row = g >> 6, d4 = g & 63;
        float4 v = reinterpret_cast<const float4*>(A)[(size_t)(base + row) * (DD / 4) + d4];
        *reinterpret_cast<float4*>(&sA[row][d4 * 4]) = v;
    }
    __syncthreads();
    if (tid < 64) out[base + tid] = np_pairwise256_sumsq(sA[tid]);
}

// ---------------------------------------------------------------------------
// Kernel 1b: fp32 -> bf16 conversion (RNE), vectorized x4. Exact grid.
// ---------------------------------------------------------------------------
__global__ __launch_bounds__(256) void f2bf4(const float4* __restrict__ src,
                                             ushort4* __restrict__ dst) {
    const int i = blockIdx.x * 256 + threadIdx.x;
    float4 v = src[i];
    ushort4 o;
    o.x = f2bf(v.x); o.y = f2bf(v.y); o.z = f2bf(v.z); o.w = f2bf(v.w);
    dst[i] = o;
}

// ---------------------------------------------------------------------------
// Kernel 1c: MFMA layout self-check (1 wave). Assumed input layouts:
//   A: lane l, elem i -> A[row = l&15][k = 8*(l>>4)+i]
//   B: lane l, elem i -> B[k = 8*(l>>4)+i][col = l&15]
// against the m89-VERIFIED C/D layout (col = lane&15, row = (lane>>4)*4+reg).
// Values vary with i (asymmetric) so both row/col-role errors AND A-vs-B
// k-pairing asymmetry are caught. Any consistent within-frag k-permutation
// (same for A and B) leaves the dot invariant -> correctly accepted.
// On failure (flag=0): minpass/candpass no-op, rescore full-scans (exact).
// ---------------------------------------------------------------------------
__global__ void mfma_check(int* __restrict__ flag) {
    const int l = threadIdx.x;          // 64 threads
    bf16x8 a, b;
    #pragma unroll
    for (int i = 0; i < 8; ++i) {
        a[i] = (short)f2bf((float)((l & 15) + 1 + i));
        b[i] = (short)f2bf((float)((l & 15) + 1 + i));
    }
    f32x4 d = {0.f, 0.f, 0.f, 0.f};
    d = __builtin_amdgcn_mfma_f32_16x16x32_bf16(a, b, d, 0, 0, 0);
    bool ok = true;
    #pragma unroll
    for (int j = 0; j < 4; ++j) {
        const int row = (l >> 4) * 4 + j;
        const int col = l & 15;
        float exp = 0.f;   // 4 lane-groups x sum_i (row+1+i)(col+1+i)
        for (int i = 0; i < 8; ++i)
            exp += (float)((row + 1 + i) * (col + 1 + i));
        exp *= 4.f;
        ok = ok && (d[j] == exp);
    }
    ok = __all(ok);
    if (l == 0) *flag = ok ? 1 : 0;
}

// ---------------------------------------------------------------------------
// Kernel 2a: MFMA approx-min pass.
//   grid 512 = 256 row-stripes(64 rows: 4 waves x 16) x 2 col-halves.
//   Per wave: A-frags (16 rows x 256 k) resident in 32 VGPRs; stream 256
//   col-tiles of 16: 8 mfma_f32_16x16x32_bf16 accumulate the full-K dot,
//   epilogue sc = (x2+c2) - 2*acc (same expression as the exact path),
//   running per-row min. Output amin2[row][half].
// ---------------------------------------------------------------------------
__global__ __launch_bounds__(256) void mfma_minpass(const unsigned short* __restrict__ Xb,
                                                    const unsigned short* __restrict__ CBb,
                                                    const float* __restrict__ c2,
                                                    const float* __restrict__ x2,
                                                    float* __restrict__ amin2,
                                                    const int* __restrict__ flag) {
    if (*flag == 0) return;
    const int tid = threadIdx.x, lane = tid & 63, wid = tid >> 6;
    const int half = blockIdx.x & 1;
    const int rowbase = (blockIdx.x >> 1) * 64 + wid * 16;
    const int colbase0 = half * 4096;

    const unsigned short* xrow = Xb + (size_t)(rowbase + (lane & 15)) * DD + (lane >> 4) * 8;
    bf16x8 afr[8];
    #pragma unroll
    for (int kb = 0; kb < 8; ++kb)
        afr[kb] = *reinterpret_cast<const bf16x8*>(xrow + kb * 32);

    float x2r[4], rmin[4];
    #pragma unroll
    for (int j = 0; j < 4; ++j) {
        x2r[j] = x2[rowbase + (lane >> 4) * 4 + j];
        rmin[j] = 3.4e38f;
    }

    for (int ct = 0; ct < 256; ++ct) {
        const int colbase = colbase0 + ct * 16;
        const unsigned short* crow = CBb + (size_t)(colbase + (lane & 15)) * DD + (lane >> 4) * 8;
        f32x4 acc = {0.f, 0.f, 0.f, 0.f};
        #pragma unroll
        for (int kb = 0; kb < 8; ++kb) {
            bf16x8 bfr = *reinterpret_cast<const bf16x8*>(crow + kb * 32);
            acc = __builtin_amdgcn_mfma_f32_16x16x32_bf16(afr[kb], bfr, acc, 0, 0, 0);
        }
        const float c2v = c2[colbase + (lane & 15)];
        #pragma unroll
        for (int j = 0; j < 4; ++j) {
            float t1 = x2r[j] + c2v;
            float sc = t1 - 2.0f * acc[j];
            rmin[j] = fminf(rmin[j], sc);
        }
    }
    #pragma unroll
    for (int j = 0; j < 4; ++j) {
        float m = rmin[j];
        #pragma unroll
        for (int s = 1; s < 16; s <<= 1) m = fminf(m, __shfl_xor(m, s, 64));
        if ((lane & 15) == 0)
            amin2[(size_t)(rowbase + (lane >> 4) * 4 + j) * 2 + half] = m;
    }
}

// ---------------------------------------------------------------------------
// Kernel 2b: MFMA candidate pass — identical compute; collects cols with
//   approx sc <= min(amin2[row][0],amin2[row][1]) + EPS via per-row atomic
//   append. Superset of {cols whose EXACT score can be the min} (error
//   bound 2.3e-4 << EPS), including all exact ties.
// ---------------------------------------------------------------------------
__global__ __launch_bounds__(256) void mfma_candpass(const unsigned short* __restrict__ Xb,
                                                     const unsigned short* __restrict__ CBb,
                                                     const float* __restrict__ c2,
                                                     const float* __restrict__ x2,
                                                     const float* __restrict__ amin2,
                                                     int* __restrict__ candcnt,
                                                     int* __restrict__ candlist,
                                                     const int* __restrict__ flag) {
    if (*flag == 0) return;
    const int tid = threadIdx.x, lane = tid & 63, wid = tid >> 6;
    const int half = blockIdx.x & 1;
    const int rowbase = (blockIdx.x >> 1) * 64 + wid * 16;
    const int colbase0 = half * 4096;

    const unsigned short* xrow = Xb + (size_t)(rowbase + (lane & 15)) * DD + (lane >> 4) * 8;
    bf16x8 afr[8];
    #pragma unroll
    for (int kb = 0; kb < 8; ++kb)
        afr[kb] = *reinterpret_cast<const bf16x8*>(xrow + kb * 32);

    float x2r[4], thr[4];
    int rowj[4];
    #pragma unroll
    for (int j = 0; j < 4; ++j) {
        rowj[j] = rowbase + (lane >> 4) * 4 + j;
        x2r[j] = x2[rowj[j]];
        thr[j] = fminf(amin2[(size_t)rowj[j] * 2], amin2[(size_t)rowj[j] * 2 + 1]) + EPS;
    }

    for (int ct = 0; ct < 256; ++ct) {
        const int colbase = colbase0 + ct * 16;
        const unsigned short* crow = CBb + (size_t)(colbase + (lane & 15)) * DD + (lane >> 4) * 8;
        f32x4 acc = {0.f, 0.f, 0.f, 0.f};
        #pragma unroll
        for (int kb = 0; kb < 8; ++kb) {
            bf16x8 bfr = *reinterpret_cast<const bf16x8*>(crow + kb * 32);
            acc = __builtin_amdgcn_mfma_f32_16x16x32_bf16(afr[kb], bfr, acc, 0, 0, 0);
        }
        const float c2v = c2[colbase + (lane & 15)];
        const int col = colbase + (lane & 15);
        #pragma unroll
        for (int j = 0; j < 4; ++j) {
            float t1 = x2r[j] + c2v;
            float sc = t1 - 2.0f * acc[j];
            if (sc <= thr[j]) {
                int idx = atomicAdd(&candcnt[rowj[j]], 1);
                if (idx < CANDCAP) candlist[(size_t)rowj[j] * CANDCAP + idx] = col;
            }
        }
    }
}

// ---------------------------------------------------------------------------
// Kernel 2c: exact rescore. One thread per row; for each candidate, the
//   VERIFIED serial fl-chain (d = 0..255 in x/y/z/w order) and the VERIFIED
//   score expression sc = (x2+c2) - 2*acc; argmin with first-index ties
//   (order-independent compare — candlist order is arbitrary).
//   Overflow (>CANDCAP) or failed layout check -> exact full scan (correct,
//   slow, expected never). Writes ids + histogram (mask=1.0, order-exact).
// ---------------------------------------------------------------------------
__global__ __launch_bounds__(256) void rescore(const float* __restrict__ X,
                                               const float* __restrict__ CB,
                                               const float* __restrict__ c2,
                                               const float* __restrict__ x2,
                                               const float* __restrict__ mask,
                                               const int* __restrict__ candcnt,
                                               const int* __restrict__ candlist,
                                               const int* __restrict__ flag,
                                               float* __restrict__ out,
                                               float* __restrict__ hist) {
    const int r = blockIdx.x * 256 + threadIdx.x;   // 16384 threads
    const float x2v = x2[r];
    const float4* xv = reinterpret_cast<const float4*>(X + (size_t)r * DD);
    const int cnt = (*flag != 0) ? candcnt[r] : (1 << 30);

    float best = 3.4e38f;
    int besti = 0;
    if (cnt <= CANDCAP) {
        for (int i = 0; i < cnt; ++i) {
            const int col = candlist[(size_t)r * CANDCAP + i];
            const float4* cv = reinterpret_cast<const float4*>(CB + (size_t)col * DD);
            float acc = 0.f;
            #pragma unroll 8
            for (int d4 = 0; d4 < 64; ++d4) {
                float4 a = xv[d4], b = cv[d4];
                acc = fmaf(a.x, b.x, acc);
                acc = fmaf(a.y, b.y, acc);
                acc = fmaf(a.z, b.z, acc);
                acc = fmaf(a.w, b.w, acc);
            }
            float t1 = x2v + c2[col];
            float sc = t1 - 2.0f * acc;
            if (sc < best || (sc == best && col < besti)) { best = sc; besti = col; }
        }
    } else {
        for (int col = 0; col < KK; ++col) {        // exact fallback, ascending
            const float4* cv = reinterpret_cast<const float4*>(CB + (size_t)col * DD);
            float acc = 0.f;
            #pragma unroll 8
            for (int d4 = 0; d4 < 64; ++d4) {
                float4 a = xv[d4], b = cv[d4];
                acc = fmaf(a.x, b.x, acc);
                acc = fmaf(a.y, b.y, acc);
                acc = fmaf(a.z, b.z, acc);
                acc = fmaf(a.w, b.w, acc);
            }
            float t1 = x2v + c2[col];
            float sc = t1 - 2.0f * acc;
            if (sc < best) { best = sc; besti = col; }   // ascending -> first-index
        }
    }
    out[OUT_IDS + r] = (float)besti;                // exact integer in float
    atomicAdd(&hist[besti], mask[r]);               // mask=1.0 -> order-exact
}

// ---------------------------------------------------------------------------
// Kernel 3: gather + MSE partials. 512 blocks x 256 threads, VERBATIM the
//   verified R0 epilogue -> partial[512] and outq/outst bit-identical.
//   Overwrites ALL scratch (Xb/CBb in OUT_Q, candlist/cnt/amin2 in OUT_ST).
// ---------------------------------------------------------------------------
__global__ __launch_bounds__(256) void vq_gather(const float* __restrict__ X,
                                                 const float* __restrict__ CB,
                                                 float* __restrict__ out,
                                                 float* __restrict__ partial) {
    __shared__ int   row_id[32];
    __shared__ float wsum[4];
    const int tid  = threadIdx.x;
    const int lane = tid & 63;
    const int wid  = tid >> 6;
    const int block_row = blockIdx.x * 32;

    if (tid < 32) row_id[tid] = (int)out[OUT_IDS + block_row + tid];
    __syncthreads();

    float msep = 0.0f;
    float* outq  = out + OUT_Q;
    float* outst = out + OUT_ST;
    #pragma unroll
    for (int i = 0; i < 8; ++i) {
        int g2 = i * 256 + tid;         // 0..2047 covers 32 rows x 64 float4
        int row = g2 >> 6;
        int d4  = g2 & 63;
        int id  = row_id[row];
        float4 q = reinterpret_cast<const float4*>(CB)[(size_t)id * (DD / 4) + d4];
        float4 x = reinterpret_cast<const float4*>(X)[(size_t)(block_row + row) * (DD / 4) + d4];
        float4 st;
        st.x = x.x + (q.x - x.x);
        st.y = x.y + (q.y - x.y);
        st.z = x.z + (q.z - x.z);
        st.w = x.w + (q.w - x.w);
        float dx = x.x - q.x; msep = fmaf(dx, dx, msep);
        dx = x.y - q.y; msep = fmaf(dx, dx, msep);
        dx = x.z - q.z; msep = fmaf(dx, dx, msep);
        dx = x.w - q.w; msep = fmaf(dx, dx, msep);
        size_t o = (size_t)(block_row + row) * (DD / 4) + d4;
        reinterpret_cast<float4*>(outq)[o]  = q;
        reinterpret_cast<float4*>(outst)[o] = st;
    }
    #pragma unroll
    for (int off = 32; off > 0; off >>= 1) msep += __shfl_down(msep, off, 64);
    if (lane == 0) wsum[wid] = msep;
    __syncthreads();
    if (tid == 0) partial[blockIdx.x] = wsum[0] + wsum[1] + wsum[2] + wsum[3];
}

// ---------------------------------------------------------------------------
// Kernel 4: finalize losses + perplexity (double precision, single block)
// ---------------------------------------------------------------------------
__global__ __launch_bounds__(256) void vq_finalize(const float* __restrict__ partial,
                                                   const float* __restrict__ hist,
                                                   float* __restrict__ out) {
    __shared__ double red[256];
    const int tid = threadIdx.x;

    double ps = 0.0;
    for (int j = tid; j < NBLOCKS; j += 256) ps += (double)partial[j];
    red[tid] = ps;
    __syncthreads();
    for (int s = 128; s > 0; s >>= 1) {
        if (tid < s) red[tid] += red[tid + s];
        __syncthreads();
    }
    double mse_sum = red[0];
    __syncthreads();

    double hs = 0.0;
    for (int j = tid; j < KK; j += 256) hs += (double)hist[j];
    red[tid] = hs;
    __syncthreads();
    for (int s = 128; s > 0; s >>= 1) {
        if (tid < s) red[tid] += red[tid + s];
        __syncthreads();
    }
    double denom = red[0] > 1.0 ? red[0] : 1.0;
    __syncthreads();

    double ent = 0.0;
    for (int j = tid; j < KK; j += 256) {
        double p = (double)hist[j] / denom;
        ent += p * log(p + 1e-8);
    }
    red[tid] = ent;
    __syncthreads();
    for (int s = 128; s > 0; s >>= 1) {
        if (tid < s) red[tid] += red[tid + s];
        __syncthreads();
    }

    if (tid == 0) {
        double mse = mse_sum / (double)((size_t)NN * DD);
        out[OUT_COMMIT] = (float)(mse * 0.25);
        out[OUT_CBL]    = (float)mse;
        out[OUT_PERP]   = (float)exp(-red[0]);
    }
}

// ---------------------------------------------------------------------------
extern "C" void kernel_launch(void* const* d_in, const int* in_sizes, int n_in,
                              void* d_out, int out_size, void* d_ws, size_t ws_size,
                              hipStream_t stream) {
    const float* latents = (const float*)d_in[0];   // [16,1024,256]
    const float* mask    = (const float*)d_in[1];   // [16,1024]
    const float* cb      = (const float*)d_in[2];   // [8192,256]
    float* out = (float*)d_out;

    // workspace (floats): hist[8192] | partial[512] | c2[8192] | x2[16384] | flag
    float* hist    = (float*)d_ws;
    float* partial = hist + KK;
    float* c2      = partial + NBLOCKS;
    float* x2      = c2 + KK;
    int*   flag    = (int*)(x2 + NN);

    // scratch in the out buffer, all fully overwritten by vq_gather:
    //   OUT_Q region : Xb bf16[NN][DD] (2,097,152 fl) + CBb bf16[KK][DD] (1,048,576 fl)
    //   OUT_ST region: candlist int[NN][64] (1,048,576 fl) + candcnt[NN] + amin2[NN][2]
    unsigned short* Xb  = (unsigned short*)(out + OUT_Q);
    unsigned short* CBb = (unsigned short*)(out + OUT_Q + 2097152);
    int*   candlist = (int*)(out + OUT_ST);
    int*   candcnt  = candlist + (size_t)NN * CANDCAP;
    float* amin2    = (float*)(candcnt + NN);

    hipMemsetAsync(hist, 0, KK * sizeof(float), stream);       // zero histogram
    hipMemsetAsync(candcnt, 0, NN * sizeof(int), stream);      // zero cand counts
    rowsumsq<<<KK / 64, 256, 0, stream>>>(cb, c2);              // numpy-exact |c|^2
    rowsumsq<<<NN / 64, 256, 0, stream>>>(latents, x2);         // numpy-exact |x|^2
    f2bf4<<<(NN * DD / 4) / 256, 256, 0, stream>>>(
        (const float4*)latents, (ushort4*)Xb);
    f2bf4<<<(KK * DD / 4) / 256, 256, 0, stream>>>(
        (const float4*)cb, (ushort4*)CBb);
    mfma_check<<<1, 64, 0, stream>>>(flag);
    mfma_minpass<<<512, 256, 0, stream>>>(Xb, CBb, c2, x2, amin2, flag);
    mfma_candpass<<<512, 256, 0, stream>>>(Xb, CBb, c2, x2, amin2,
                                           candcnt, candlist, flag);
    rescore<<<NN / 256, 256, 0, stream>>>(latents, cb, c2, x2, mask,
                                          candcnt, candlist, flag, out, hist);
    vq_gather<<<NBLOCKS, 256, 0, stream>>>(latents, cb, out, partial);
    vq_finalize<<<1, 256, 0, stream>>>(partial, hist, out);
}

// Round 11
// 1887.045 us; speedup vs baseline: 12.7145x; 12.7145x over previous
//
#include <hip/hip_runtime.h>
#include <math.h>

// Problem constants
#define DD 256            // latent dim
#define KK 8192           // codebook size
#define NN 16384          // rows
#define NBLOCKS 512       // gather/partial grid (verified 32-row geometry)
#define RSTRIDE 260       // rowsumsq staging stride (unchanged, verified)
#define EPS 2e-3f         // 1.7x margin over the 1.2e-3 two-sided hard error bound
#define CANDCAP 128       // per-row candidate cap (mean ~22; P(overflow) ~ 1 row/run)

// Output layout (all float32, concatenated in reference return order)
#define OUT_IDS   0
#define OUT_Q     16384
#define OUT_ST    4210688          // 16384 + 4194304
#define OUT_COMMIT 8404992
#define OUT_CBL    8404993
#define OUT_PERP   8404994

// MFMA fragment types (per guide §3: verified on gfx950)
using bf16x8 = __attribute__((ext_vector_type(8))) short;
using f32x4  = __attribute__((ext_vector_type(4))) float;

// fp32 -> bf16 RNE (finite inputs; bit pattern in ushort)
__device__ __forceinline__ unsigned short f2bf(float f) {
    unsigned u = __float_as_uint(f);
    return (unsigned short)((u + 0x7FFFu + ((u >> 16) & 1u)) >> 16);
}

// ---------------------------------------------------------------------------
// numpy pairwise-sum replica for sum of squares (verified bit-exact)
// ---------------------------------------------------------------------------
__device__ __forceinline__ float np_block128_sumsq(const float* p) {
    #pragma clang fp contract(off)
    float r0 = p[0] * p[0], r1 = p[1] * p[1], r2 = p[2] * p[2], r3 = p[3] * p[3];
    float r4 = p[4] * p[4], r5 = p[5] * p[5], r6 = p[6] * p[6], r7 = p[7] * p[7];
    for (int i = 8; i < 128; i += 8) {
        r0 = r0 + p[i + 0] * p[i + 0];
        r1 = r1 + p[i + 1] * p[i + 1];
        r2 = r2 + p[i + 2] * p[i + 2];
        r3 = r3 + p[i + 3] * p[i + 3];
        r4 = r4 + p[i + 4] * p[i + 4];
        r5 = r5 + p[i + 5] * p[i + 5];
        r6 = r6 + p[i + 6] * p[i + 6];
        r7 = r7 + p[i + 7] * p[i + 7];
    }
    return ((r0 + r1) + (r2 + r3)) + ((r4 + r5) + (r6 + r7));
}

__device__ __forceinline__ float np_pairwise256_sumsq(const float* a) {
    #pragma clang fp contract(off)
    float s0 = np_block128_sumsq(a);
    float s1 = np_block128_sumsq(a + 128);
    return s0 + s1;
}

// ---------------------------------------------------------------------------
// Kernel 1: per-row sum of squares, numpy-pairwise-exact (unchanged, verified)
// ---------------------------------------------------------------------------
__global__ __launch_bounds__(256) void rowsumsq(const float* __restrict__ A,
                                                float* __restrict__ out) {
    __shared__ __align__(16) float sA[64][RSTRIDE];
    const int tid = threadIdx.x;
    const int base = blockIdx.x * 64;
    #pragma unroll
    for (int i = 0; i < 16; ++i) {
        int g = i * 256 + tid;
        int row = g >> 6, d4 = g & 63;
        float4 v = reinterpret_cast<const float4*>(A)[(size_t)(base + row) * (DD / 4) + d4];
        *reinterpret_cast<float4*>(&sA[row][d4 * 4]) = v;
    }
    __syncthreads();
    if (tid < 64) out[base + tid] = np_pairwise256_sumsq(sA[tid]);
}

// ---------------------------------------------------------------------------
// Kernel 1b: fp32 -> bf16 conversion (RNE), vectorized x4. Exact grid.
// ---------------------------------------------------------------------------
__global__ __launch_bounds__(256) void f2bf4(const float4* __restrict__ src,
                                             ushort4* __restrict__ dst) {
    const int i = blockIdx.x * 256 + threadIdx.x;
    float4 v = src[i];
    ushort4 o;
    o.x = f2bf(v.x); o.y = f2bf(v.y); o.z = f2bf(v.z); o.w = f2bf(v.w);
    dst[i] = o;
}

// ---------------------------------------------------------------------------
// Kernel 1c: MFMA layout self-check (1 wave). Accepts any layout of the form
//   A: lane = row + 16*g(k), elem e(k);  B: lane = col + 16*g(k), elem e(k)
// with a SHARED (g,e) bijection — under which minpass/candpass dots are
// permutation-invariant and thus correct. Fails only on A/B-asymmetric or
// role-swapped layouts; then rescore full-scans (exact, wave-parallel).
// ---------------------------------------------------------------------------
__global__ void mfma_check(int* __restrict__ flag) {
    const int l = threadIdx.x;          // 64 threads
    bf16x8 a, b;
    #pragma unroll
    for (int i = 0; i < 8; ++i) {
        a[i] = (short)f2bf((float)((l & 15) + 1 + i));
        b[i] = (short)f2bf((float)((l & 15) + 1 + i));
    }
    f32x4 d = {0.f, 0.f, 0.f, 0.f};
    d = __builtin_amdgcn_mfma_f32_16x16x32_bf16(a, b, d, 0, 0, 0);
    bool ok = true;
    #pragma unroll
    for (int j = 0; j < 4; ++j) {
        const int row = (l >> 4) * 4 + j;
        const int col = l & 15;
        float exp = 0.f;   // 4 lane-groups x sum_i (row+1+i)(col+1+i)
        for (int i = 0; i < 8; ++i)
            exp += (float)((row + 1 + i) * (col + 1 + i));
        exp *= 4.f;
        ok = ok && (d[j] == exp);
    }
    ok = __all(ok);
    if (l == 0) *flag = ok ? 1 : 0;
}

// ---------------------------------------------------------------------------
// Kernel 2a: MFMA approx-min pass.
//   grid 512 = 256 row-stripes(64 rows: 4 waves x 16) x 2 col-halves.
//   Per wave: A-frags (16 rows x 256 k) resident in 32 VGPRs; stream 256
//   col-tiles of 16: 8 mfma_f32_16x16x32_bf16 accumulate the full-K dot,
//   epilogue sc = (x2+c2) - 2*acc, running per-row min -> amin2[row][half].
// ---------------------------------------------------------------------------
__global__ __launch_bounds__(256) void mfma_minpass(const unsigned short* __restrict__ Xb,
                                                    const unsigned short* __restrict__ CBb,
                                                    const float* __restrict__ c2,
                                                    const float* __restrict__ x2,
                                                    float* __restrict__ amin2,
                                                    const int* __restrict__ flag) {
    if (*flag == 0) return;
    const int tid = threadIdx.x, lane = tid & 63, wid = tid >> 6;
    const int half = blockIdx.x & 1;
    const int rowbase = (blockIdx.x >> 1) * 64 + wid * 16;
    const int colbase0 = half * 4096;

    const unsigned short* xrow = Xb + (size_t)(rowbase + (lane & 15)) * DD + (lane >> 4) * 8;
    bf16x8 afr[8];
    #pragma unroll
    for (int kb = 0; kb < 8; ++kb)
        afr[kb] = *reinterpret_cast<const bf16x8*>(xrow + kb * 32);

    float x2r[4], rmin[4];
    #pragma unroll
    for (int j = 0; j < 4; ++j) {
        x2r[j] = x2[rowbase + (lane >> 4) * 4 + j];
        rmin[j] = 3.4e38f;
    }

    for (int ct = 0; ct < 256; ++ct) {
        const int colbase = colbase0 + ct * 16;
        const unsigned short* crow = CBb + (size_t)(colbase + (lane & 15)) * DD + (lane >> 4) * 8;
        f32x4 acc = {0.f, 0.f, 0.f, 0.f};
        #pragma unroll
        for (int kb = 0; kb < 8; ++kb) {
            bf16x8 bfr = *reinterpret_cast<const bf16x8*>(crow + kb * 32);
            acc = __builtin_amdgcn_mfma_f32_16x16x32_bf16(afr[kb], bfr, acc, 0, 0, 0);
        }
        const float c2v = c2[colbase + (lane & 15)];
        #pragma unroll
        for (int j = 0; j < 4; ++j) {
            float t1 = x2r[j] + c2v;
            float sc = t1 - 2.0f * acc[j];
            rmin[j] = fminf(rmin[j], sc);
        }
    }
    #pragma unroll
    for (int j = 0; j < 4; ++j) {
        float m = rmin[j];
        #pragma unroll
        for (int s = 1; s < 16; s <<= 1) m = fminf(m, __shfl_xor(m, s, 64));
        if ((lane & 15) == 0)
            amin2[(size_t)(rowbase + (lane >> 4) * 4 + j) * 2 + half] = m;
    }
}

// ---------------------------------------------------------------------------
// Kernel 2b: MFMA candidate pass — identical compute; collects cols with
//   approx sc <= min(amin2[row][0],amin2[row][1]) + EPS via per-row atomic
//   append. Superset of all cols whose EXACT score can be the min (2-sided
//   bound 1.2e-3 < EPS), including all exact ties.
// ---------------------------------------------------------------------------
__global__ __launch_bounds__(256) void mfma_candpass(const unsigned short* __restrict__ Xb,
                                                     const unsigned short* __restrict__ CBb,
                                                     const float* __restrict__ c2,
                                                     const float* __restrict__ x2,
                                                     const float* __restrict__ amin2,
                                                     int* __restrict__ candcnt,
                                                     int* __restrict__ candlist,
                                                     const int* __restrict__ flag) {
    if (*flag == 0) return;
    const int tid = threadIdx.x, lane = tid & 63, wid = tid >> 6;
    const int half = blockIdx.x & 1;
    const int rowbase = (blockIdx.x >> 1) * 64 + wid * 16;
    const int colbase0 = half * 4096;

    const unsigned short* xrow = Xb + (size_t)(rowbase + (lane & 15)) * DD + (lane >> 4) * 8;
    bf16x8 afr[8];
    #pragma unroll
    for (int kb = 0; kb < 8; ++kb)
        afr[kb] = *reinterpret_cast<const bf16x8*>(xrow + kb * 32);

    float x2r[4], thr[4];
    int rowj[4];
    #pragma unroll
    for (int j = 0; j < 4; ++j) {
        rowj[j] = rowbase + (lane >> 4) * 4 + j;
        x2r[j] = x2[rowj[j]];
        thr[j] = fminf(amin2[(size_t)rowj[j] * 2], amin2[(size_t)rowj[j] * 2 + 1]) + EPS;
    }

    for (int ct = 0; ct < 256; ++ct) {
        const int colbase = colbase0 + ct * 16;
        const unsigned short* crow = CBb + (size_t)(colbase + (lane & 15)) * DD + (lane >> 4) * 8;
        f32x4 acc = {0.f, 0.f, 0.f, 0.f};
        #pragma unroll
        for (int kb = 0; kb < 8; ++kb) {
            bf16x8 bfr = *reinterpret_cast<const bf16x8*>(crow + kb * 32);
            acc = __builtin_amdgcn_mfma_f32_16x16x32_bf16(afr[kb], bfr, acc, 0, 0, 0);
        }
        const float c2v = c2[colbase + (lane & 15)];
        const int col = colbase + (lane & 15);
        #pragma unroll
        for (int j = 0; j < 4; ++j) {
            float t1 = x2r[j] + c2v;
            float sc = t1 - 2.0f * acc[j];
            if (sc <= thr[j]) {
                int idx = atomicAdd(&candcnt[rowj[j]], 1);
                if (idx < CANDCAP) candlist[(size_t)rowj[j] * CANDCAP + idx] = col;
            }
        }
    }
}

// ---------------------------------------------------------------------------
// Kernel 2c: exact rescore — ROUND-11: WAVE-PARALLEL (one wave per row).
//   R10's thread-serial rescore made any fallback/overflow row a 20ms
//   straggler. Now: candidate path = lane i rescores candidate i with the
//   VERIFIED serial fl-chain (d=0..255, x/y/z/w) + verified score expression;
//   fallback path (overflow or flag=0) = lane scans col=lane+64j ascending —
//   EXACTLY R0's verified per-row wave semantics. Butterfly argmin with the
//   verified first-index tie rule. Worst case per row: ~60us, not 20ms.
// ---------------------------------------------------------------------------
__global__ __launch_bounds__(256) void rescore(const float* __restrict__ X,
                                               const float* __restrict__ CB,
                                               const float* __restrict__ c2,
                                               const float* __restrict__ x2,
                                               const float* __restrict__ mask,
                                               const int* __restrict__ candcnt,
                                               const int* __restrict__ candlist,
                                               const int* __restrict__ flag,
                                               float* __restrict__ out,
                                               float* __restrict__ hist) {
    const int tid = threadIdx.x, lane = tid & 63, wid = tid >> 6;
    const int r = blockIdx.x * 4 + wid;             // 4096 blocks x 4 waves
    const float x2v = x2[r];
    const float4* xv = reinterpret_cast<const float4*>(X + (size_t)r * DD);
    const int cnt = (*flag != 0) ? candcnt[r] : (1 << 30);

    float best = 3.4e38f;
    int besti = 0;
    if (cnt <= CANDCAP) {
        for (int i = lane; i < cnt; i += 64) {
            const int col = candlist[(size_t)r * CANDCAP + i];
            const float4* cv = reinterpret_cast<const float4*>(CB + (size_t)col * DD);
            float acc = 0.f;
            #pragma unroll 8
            for (int d4 = 0; d4 < 64; ++d4) {
                float4 a = xv[d4], b = cv[d4];
                acc = fmaf(a.x, b.x, acc);
                acc = fmaf(a.y, b.y, acc);
                acc = fmaf(a.z, b.z, acc);
                acc = fmaf(a.w, b.w, acc);
            }
            float t1 = x2v + c2[col];
            float sc = t1 - 2.0f * acc;
            if (sc < best || (sc == best && col < besti)) { best = sc; besti = col; }
        }
    } else {
        for (int j = 0; j < KK / 64; ++j) {          // ascending cols per lane
            const int col = lane + 64 * j;
            const float4* cv = reinterpret_cast<const float4*>(CB + (size_t)col * DD);
            float acc = 0.f;
            #pragma unroll 8
            for (int d4 = 0; d4 < 64; ++d4) {
                float4 a = xv[d4], b = cv[d4];
                acc = fmaf(a.x, b.x, acc);
                acc = fmaf(a.y, b.y, acc);
                acc = fmaf(a.z, b.z, acc);
                acc = fmaf(a.w, b.w, acc);
            }
            float t1 = x2v + c2[col];
            float sc = t1 - 2.0f * acc;
            if (sc < best || (sc == best && col < besti)) { best = sc; besti = col; }
        }
    }
    // wave argmin, first-index ties (verified butterfly)
    #pragma unroll
    for (int m = 32; m > 0; m >>= 1) {
        float b2 = __shfl_xor(best, m, 64);
        int   i2 = __shfl_xor(besti, m, 64);
        if (b2 < best || (b2 == best && i2 < besti)) { best = b2; besti = i2; }
    }
    if (lane == 0) {
        out[OUT_IDS + r] = (float)besti;            // exact integer in float
        atomicAdd(&hist[besti], mask[r]);           // mask=1.0 -> order-exact
    }
}

// ---------------------------------------------------------------------------
// Kernel 3: gather + MSE partials. 512 blocks x 256 threads, VERBATIM the
//   verified R0 epilogue -> partial[512] and outq/outst bit-identical.
//   Overwrites ALL scratch (Xb/CBb in OUT_Q; candlist/cnt/amin2/flag in OUT_ST).
// ---------------------------------------------------------------------------
__global__ __launch_bounds__(256) void vq_gather(const float* __restrict__ X,
                                                 const float* __restrict__ CB,
                                                 float* __restrict__ out,
                                                 float* __restrict__ partial) {
    __shared__ int   row_id[32];
    __shared__ float wsum[4];
    const int tid  = threadIdx.x;
    const int lane = tid & 63;
    const int wid  = tid >> 6;
    const int block_row = blockIdx.x * 32;

    if (tid < 32) row_id[tid] = (int)out[OUT_IDS + block_row + tid];
    __syncthreads();

    float msep = 0.0f;
    float* outq  = out + OUT_Q;
    float* outst = out + OUT_ST;
    #pragma unroll
    for (int i = 0; i < 8; ++i) {
        int g2 = i * 256 + tid;         // 0..2047 covers 32 rows x 64 float4
        int row = g2 >> 6;
        int d4  = g2 & 63;
        int id  = row_id[row];
        float4 q = reinterpret_cast<const float4*>(CB)[(size_t)id * (DD / 4) + d4];
        float4 x = reinterpret_cast<const float4*>(X)[(size_t)(block_row + row) * (DD / 4) + d4];
        float4 st;
        st.x = x.x + (q.x - x.x);
        st.y = x.y + (q.y - x.y);
        st.z = x.z + (q.z - x.z);
        st.w = x.w + (q.w - x.w);
        float dx = x.x - q.x; msep = fmaf(dx, dx, msep);
        dx = x.y - q.y; msep = fmaf(dx, dx, msep);
        dx = x.z - q.z; msep = fmaf(dx, dx, msep);
        dx = x.w - q.w; msep = fmaf(dx, dx, msep);
        size_t o = (size_t)(block_row + row) * (DD / 4) + d4;
        reinterpret_cast<float4*>(outq)[o]  = q;
        reinterpret_cast<float4*>(outst)[o] = st;
    }
    #pragma unroll
    for (int off = 32; off > 0; off >>= 1) msep += __shfl_down(msep, off, 64);
    if (lane == 0) wsum[wid] = msep;
    __syncthreads();
    if (tid == 0) partial[blockIdx.x] = wsum[0] + wsum[1] + wsum[2] + wsum[3];
}

// ---------------------------------------------------------------------------
// Kernel 4: finalize losses + perplexity (double precision, single block)
// ---------------------------------------------------------------------------
__global__ __launch_bounds__(256) void vq_finalize(const float* __restrict__ partial,
                                                   const float* __restrict__ hist,
                                                   float* __restrict__ out) {
    __shared__ double red[256];
    const int tid = threadIdx.x;

    double ps = 0.0;
    for (int j = tid; j < NBLOCKS; j += 256) ps += (double)partial[j];
    red[tid] = ps;
    __syncthreads();
    for (int s = 128; s > 0; s >>= 1) {
        if (tid < s) red[tid] += red[tid + s];
        __syncthreads();
    }
    double mse_sum = red[0];
    __syncthreads();

    double hs = 0.0;
    for (int j = tid; j < KK; j += 256) hs += (double)hist[j];
    red[tid] = hs;
    __syncthreads();
    for (int s = 128; s > 0; s >>= 1) {
        if (tid < s) red[tid] += red[tid + s];
        __syncthreads();
    }
    double denom = red[0] > 1.0 ? red[0] : 1.0;
    __syncthreads();

    double ent = 0.0;
    for (int j = tid; j < KK; j += 256) {
        double p = (double)hist[j] / denom;
        ent += p * log(p + 1e-8);
    }
    red[tid] = ent;
    __syncthreads();
    for (int s = 128; s > 0; s >>= 1) {
        if (tid < s) red[tid] += red[tid + s];
        __syncthreads();
    }

    if (tid == 0) {
        double mse = mse_sum / (double)((size_t)NN * DD);
        out[OUT_COMMIT] = (float)(mse * 0.25);
        out[OUT_CBL]    = (float)mse;
        out[OUT_PERP]   = (float)exp(-red[0]);
    }
}

// ---------------------------------------------------------------------------
extern "C" void kernel_launch(void* const* d_in, const int* in_sizes, int n_in,
                              void* d_out, int out_size, void* d_ws, size_t ws_size,
                              hipStream_t stream) {
    const float* latents = (const float*)d_in[0];   // [16,1024,256]
    const float* mask    = (const float*)d_in[1];   // [16,1024]
    const float* cb      = (const float*)d_in[2];   // [8192,256]
    float* out = (float*)d_out;

    // workspace (floats): hist[8192] | partial[512] | c2[8192] | x2[16384]
    // (back to the verified 33,280-float footprint; flag moved to out scratch)
    float* hist    = (float*)d_ws;
    float* partial = hist + KK;
    float* c2      = partial + NBLOCKS;
    float* x2      = c2 + KK;

    // scratch in the out buffer, all fully overwritten by vq_gather:
    //   OUT_Q region : Xb bf16[NN][DD] (2,097,152 fl) + CBb bf16[KK][DD] (1,048,576 fl)
    //   OUT_ST region: candlist int[NN][128] (2,097,152 fl) + candcnt[NN]
    //                  + amin2[NN][2] + flag  (total 2,146,305 <= 4,194,304)
    unsigned short* Xb  = (unsigned short*)(out + OUT_Q);
    unsigned short* CBb = (unsigned short*)(out + OUT_Q + 2097152);
    int*   candlist = (int*)(out + OUT_ST);
    int*   candcnt  = candlist + (size_t)NN * CANDCAP;
    float* amin2    = (float*)(candcnt + NN);
    int*   flag     = (int*)(amin2 + 2 * NN);

    hipMemsetAsync(hist, 0, KK * sizeof(float), stream);       // zero histogram
    hipMemsetAsync(candcnt, 0, NN * sizeof(int), stream);      // zero cand counts
    rowsumsq<<<KK / 64, 256, 0, stream>>>(cb, c2);              // numpy-exact |c|^2
    rowsumsq<<<NN / 64, 256, 0, stream>>>(latents, x2);         // numpy-exact |x|^2
    f2bf4<<<(NN * DD / 4) / 256, 256, 0, stream>>>(
        (const float4*)latents, (ushort4*)Xb);
    f2bf4<<<(KK * DD / 4) / 256, 256, 0, stream>>>(
        (const float4*)cb, (ushort4*)CBb);
    mfma_check<<<1, 64, 0, stream>>>(flag);
    mfma_minpass<<<512, 256, 0, stream>>>(Xb, CBb, c2, x2, amin2, flag);
    mfma_candpass<<<512, 256, 0, stream>>>(Xb, CBb, c2, x2, amin2,
                                           candcnt, candlist, flag);
    rescore<<<NN / 4, 256, 0, stream>>>(latents, cb, c2, x2, mask,
                                        candcnt, candlist, flag, out, hist);
    vq_gather<<<NBLOCKS, 256, 0, stream>>>(latents, cb, out, partial);
    vq_finalize<<<1, 256, 0, stream>>>(partial, hist, out);
}

// Round 12
// 1321.965 us; speedup vs baseline: 18.1494x; 1.4275x over previous
//
#include <hip/hip_runtime.h>
#include <math.h>

// Problem constants
#define DD 256            // latent dim
#define KK 8192           // codebook size
#define NN 16384          // rows
#define NBLOCKS 512       // gather/partial grid (verified 32-row geometry)
#define RSTRIDE 260       // rowsumsq staging stride (unchanged, verified)
#define EPS 2e-3f         // 1.7x margin over the bf16 approx-error hard bound
#define CANDCAP 128       // per-row candidate cap (mean ~17; overflow -> worklist)

// Output layout (all float32, concatenated in reference return order)
#define OUT_IDS   0
#define OUT_Q     16384
#define OUT_ST    4210688          // 16384 + 4194304
#define OUT_COMMIT 8404992
#define OUT_CBL    8404993
#define OUT_PERP   8404994

// MFMA fragment types (per guide §3: verified on gfx950)
using bf16x8 = __attribute__((ext_vector_type(8))) short;
using f32x4  = __attribute__((ext_vector_type(4))) float;

// fp32 -> bf16 RNE (finite inputs; bit pattern in ushort)
__device__ __forceinline__ unsigned short f2bf(float f) {
    unsigned u = __float_as_uint(f);
    return (unsigned short)((u + 0x7FFFu + ((u >> 16) & 1u)) >> 16);
}

// ---------------------------------------------------------------------------
// numpy pairwise-sum replica for sum of squares (verified bit-exact)
// ---------------------------------------------------------------------------
__device__ __forceinline__ float np_block128_sumsq(const float* p) {
    #pragma clang fp contract(off)
    float r0 = p[0] * p[0], r1 = p[1] * p[1], r2 = p[2] * p[2], r3 = p[3] * p[3];
    float r4 = p[4] * p[4], r5 = p[5] * p[5], r6 = p[6] * p[6], r7 = p[7] * p[7];
    for (int i = 8; i < 128; i += 8) {
        r0 = r0 + p[i + 0] * p[i + 0];
        r1 = r1 + p[i + 1] * p[i + 1];
        r2 = r2 + p[i + 2] * p[i + 2];
        r3 = r3 + p[i + 3] * p[i + 3];
        r4 = r4 + p[i + 4] * p[i + 4];
        r5 = r5 + p[i + 5] * p[i + 5];
        r6 = r6 + p[i + 6] * p[i + 6];
        r7 = r7 + p[i + 7] * p[i + 7];
    }
    return ((r0 + r1) + (r2 + r3)) + ((r4 + r5) + (r6 + r7));
}

__device__ __forceinline__ float np_pairwise256_sumsq(const float* a) {
    #pragma clang fp contract(off)
    float s0 = np_block128_sumsq(a);
    float s1 = np_block128_sumsq(a + 128);
    return s0 + s1;
}

// ---------------------------------------------------------------------------
// Kernel 1: per-row sum of squares, numpy-pairwise-exact (unchanged, verified)
// ---------------------------------------------------------------------------
__global__ __launch_bounds__(256) void rowsumsq(const float* __restrict__ A,
                                                float* __restrict__ out) {
    __shared__ __align__(16) float sA[64][RSTRIDE];
    const int tid = threadIdx.x;
    const int base = blockIdx.x * 64;
    #pragma unroll
    for (int i = 0; i < 16; ++i) {
        int g = i * 256 + tid;
        int row = g >> 6, d4 = g & 63;
        float4 v = reinterpret_cast<const float4*>(A)[(size_t)(base + row) * (DD / 4) + d4];
        *reinterpret_cast<float4*>(&sA[row][d4 * 4]) = v;
    }
    __syncthreads();
    if (tid < 64) out[base + tid] = np_pairwise256_sumsq(sA[tid]);
}

// ---------------------------------------------------------------------------
// Kernel 1b: fp32 -> bf16 conversion (RNE), vectorized x4. Exact grid.
// ---------------------------------------------------------------------------
__global__ __launch_bounds__(256) void f2bf4(const float4* __restrict__ src,
                                             ushort4* __restrict__ dst) {
    const int i = blockIdx.x * 256 + threadIdx.x;
    float4 v = src[i];
    ushort4 o;
    o.x = f2bf(v.x); o.y = f2bf(v.y); o.z = f2bf(v.z); o.w = f2bf(v.w);
    dst[i] = o;
}

// ---------------------------------------------------------------------------
// Kernel 1c: MFMA layout self-check (1 wave) — verified working in R11
// (flag=1 evidenced by rescore's low-occupancy straggler profile, not a
// full-scan-everywhere profile). On failure: all rows route to the
// bounded-parallel overflow path (exact, ~0.5 ms).
// ---------------------------------------------------------------------------
__global__ void mfma_check(int* __restrict__ flag) {
    const int l = threadIdx.x;          // 64 threads
    bf16x8 a, b;
    #pragma unroll
    for (int i = 0; i < 8; ++i) {
        a[i] = (short)f2bf((float)((l & 15) + 1 + i));
        b[i] = (short)f2bf((float)((l & 15) + 1 + i));
    }
    f32x4 d = {0.f, 0.f, 0.f, 0.f};
    d = __builtin_amdgcn_mfma_f32_16x16x32_bf16(a, b, d, 0, 0, 0);
    bool ok = true;
    #pragma unroll
    for (int j = 0; j < 4; ++j) {
        const int row = (l >> 4) * 4 + j;
        const int col = l & 15;
        float exp = 0.f;
        for (int i = 0; i < 8; ++i)
            exp += (float)((row + 1 + i) * (col + 1 + i));
        exp *= 4.f;
        ok = ok && (d[j] == exp);
    }
    ok = __all(ok);
    if (l == 0) *flag = ok ? 1 : 0;
}

// ---------------------------------------------------------------------------
// Kernel 2a: MFMA approx-min pass (unchanged from R11, verified).
// ---------------------------------------------------------------------------
__global__ __launch_bounds__(256) void mfma_minpass(const unsigned short* __restrict__ Xb,
                                                    const unsigned short* __restrict__ CBb,
                                                    const float* __restrict__ c2,
                                                    const float* __restrict__ x2,
                                                    float* __restrict__ amin2,
                                                    const int* __restrict__ flag) {
    if (*flag == 0) return;
    const int tid = threadIdx.x, lane = tid & 63, wid = tid >> 6;
    const int half = blockIdx.x & 1;
    const int rowbase = (blockIdx.x >> 1) * 64 + wid * 16;
    const int colbase0 = half * 4096;

    const unsigned short* xrow = Xb + (size_t)(rowbase + (lane & 15)) * DD + (lane >> 4) * 8;
    bf16x8 afr[8];
    #pragma unroll
    for (int kb = 0; kb < 8; ++kb)
        afr[kb] = *reinterpret_cast<const bf16x8*>(xrow + kb * 32);

    float x2r[4], rmin[4];
    #pragma unroll
    for (int j = 0; j < 4; ++j) {
        x2r[j] = x2[rowbase + (lane >> 4) * 4 + j];
        rmin[j] = 3.4e38f;
    }

    for (int ct = 0; ct < 256; ++ct) {
        const int colbase = colbase0 + ct * 16;
        const unsigned short* crow = CBb + (size_t)(colbase + (lane & 15)) * DD + (lane >> 4) * 8;
        f32x4 acc = {0.f, 0.f, 0.f, 0.f};
        #pragma unroll
        for (int kb = 0; kb < 8; ++kb) {
            bf16x8 bfr = *reinterpret_cast<const bf16x8*>(crow + kb * 32);
            acc = __builtin_amdgcn_mfma_f32_16x16x32_bf16(afr[kb], bfr, acc, 0, 0, 0);
        }
        const float c2v = c2[colbase + (lane & 15)];
        #pragma unroll
        for (int j = 0; j < 4; ++j) {
            float t1 = x2r[j] + c2v;
            float sc = t1 - 2.0f * acc[j];
            rmin[j] = fminf(rmin[j], sc);
        }
    }
    #pragma unroll
    for (int j = 0; j < 4; ++j) {
        float m = rmin[j];
        #pragma unroll
        for (int s = 1; s < 16; s <<= 1) m = fminf(m, __shfl_xor(m, s, 64));
        if ((lane & 15) == 0)
            amin2[(size_t)(rowbase + (lane >> 4) * 4 + j) * 2 + half] = m;
    }
}

// ---------------------------------------------------------------------------
// Kernel 2b: MFMA candidate pass (unchanged from R11, verified).
// ---------------------------------------------------------------------------
__global__ __launch_bounds__(256) void mfma_candpass(const unsigned short* __restrict__ Xb,
                                                     const unsigned short* __restrict__ CBb,
                                                     const float* __restrict__ c2,
                                                     const float* __restrict__ x2,
                                                     const float* __restrict__ amin2,
                                                     int* __restrict__ candcnt,
                                                     int* __restrict__ candlist,
                                                     const int* __restrict__ flag) {
    if (*flag == 0) return;
    const int tid = threadIdx.x, lane = tid & 63, wid = tid >> 6;
    const int half = blockIdx.x & 1;
    const int rowbase = (blockIdx.x >> 1) * 64 + wid * 16;
    const int colbase0 = half * 4096;

    const unsigned short* xrow = Xb + (size_t)(rowbase + (lane & 15)) * DD + (lane >> 4) * 8;
    bf16x8 afr[8];
    #pragma unroll
    for (int kb = 0; kb < 8; ++kb)
        afr[kb] = *reinterpret_cast<const bf16x8*>(xrow + kb * 32);

    float x2r[4], thr[4];
    int rowj[4];
    #pragma unroll
    for (int j = 0; j < 4; ++j) {
        rowj[j] = rowbase + (lane >> 4) * 4 + j;
        x2r[j] = x2[rowj[j]];
        thr[j] = fminf(amin2[(size_t)rowj[j] * 2], amin2[(size_t)rowj[j] * 2 + 1]) + EPS;
    }

    for (int ct = 0; ct < 256; ++ct) {
        const int colbase = colbase0 + ct * 16;
        const unsigned short* crow = CBb + (size_t)(colbase + (lane & 15)) * DD + (lane >> 4) * 8;
        f32x4 acc = {0.f, 0.f, 0.f, 0.f};
        #pragma unroll
        for (int kb = 0; kb < 8; ++kb) {
            bf16x8 bfr = *reinterpret_cast<const bf16x8*>(crow + kb * 32);
            acc = __builtin_amdgcn_mfma_f32_16x16x32_bf16(afr[kb], bfr, acc, 0, 0, 0);
        }
        const float c2v = c2[colbase + (lane & 15)];
        const int col = colbase + (lane & 15);
        #pragma unroll
        for (int j = 0; j < 4; ++j) {
            float t1 = x2r[j] + c2v;
            float sc = t1 - 2.0f * acc[j];
            if (sc <= thr[j]) {
                int idx = atomicAdd(&candcnt[rowj[j]], 1);
                if (idx < CANDCAP) candlist[(size_t)rowj[j] * CANDCAP + idx] = col;
            }
        }
    }
}

// ---------------------------------------------------------------------------
// Kernel 2c: exact rescore — ROUND-12: overflow rows no longer scan serially;
//   they are appended to a worklist and handled by vq_overflow (bounded
//   parallel). Candidate path unchanged (verified): lane i rescores candidate
//   i with the verified fl-chain; butterfly argmin, first-index ties.
// ---------------------------------------------------------------------------
__global__ __launch_bounds__(256) void rescore(const float* __restrict__ X,
                                               const float* __restrict__ CB,
                                               const float* __restrict__ c2,
                                               const float* __restrict__ x2,
                                               const float* __restrict__ mask,
                                               const int* __restrict__ candcnt,
                                               const int* __restrict__ candlist,
                                               const int* __restrict__ flag,
                                               int* __restrict__ novercnt,
                                               int* __restrict__ worklist,
                                               float* __restrict__ out,
                                               float* __restrict__ hist) {
    const int tid = threadIdx.x, lane = tid & 63, wid = tid >> 6;
    const int r = blockIdx.x * 4 + wid;             // 4096 blocks x 4 waves
    const int cnt = (*flag != 0) ? candcnt[r] : (1 << 30);

    if (cnt <= CANDCAP) {
        const float x2v = x2[r];
        const float4* xv = reinterpret_cast<const float4*>(X + (size_t)r * DD);
        float best = 3.4e38f;
        int besti = 0;
        for (int i = lane; i < cnt; i += 64) {
            const int col = candlist[(size_t)r * CANDCAP + i];
            const float4* cv = reinterpret_cast<const float4*>(CB + (size_t)col * DD);
            float acc = 0.f;
            #pragma unroll 8
            for (int d4 = 0; d4 < 64; ++d4) {
                float4 a = xv[d4], b = cv[d4];
                acc = fmaf(a.x, b.x, acc);
                acc = fmaf(a.y, b.y, acc);
                acc = fmaf(a.z, b.z, acc);
                acc = fmaf(a.w, b.w, acc);
            }
            float t1 = x2v + c2[col];
            float sc = t1 - 2.0f * acc;
            if (sc < best || (sc == best && col < besti)) { best = sc; besti = col; }
        }
        #pragma unroll
        for (int m = 32; m > 0; m >>= 1) {
            float b2 = __shfl_xor(best, m, 64);
            int   i2 = __shfl_xor(besti, m, 64);
            if (b2 < best || (b2 == best && i2 < besti)) { best = b2; besti = i2; }
        }
        if (lane == 0) {
            out[OUT_IDS + r] = (float)besti;        // exact integer in float
            atomicAdd(&hist[besti], mask[r]);       // mask=1.0 -> order-exact
        }
    } else {
        if (lane == 0) {
            int oi = atomicAdd(novercnt, 1);
            worklist[oi] = r;
        }
    }
}

// ---------------------------------------------------------------------------
// Kernel 2d: bounded-parallel exact full scan for overflow rows.
//   Work item = (overflow row, 64-col chunk): 128 items per row, each a wave
//   computing the VERIFIED exact chain for 1 col/lane + butterfly argmin,
//   folded via packed atomicMin (score_bits<<32 | col). Scores are positive
//   (x2 ~ 256 dominates) -> uint compare == float compare; equal scores pick
//   lower col == first-index tie rule. One row completes in ~3us (128
//   concurrent waves) instead of R11's 700us single-wave scan.
// ---------------------------------------------------------------------------
__global__ __launch_bounds__(256) void vq_overflow(const float* __restrict__ X,
                                                   const float* __restrict__ CB,
                                                   const float* __restrict__ c2,
                                                   const float* __restrict__ x2,
                                                   const int* __restrict__ novercnt,
                                                   const int* __restrict__ worklist,
                                                   unsigned long long* __restrict__ packedbest) {
    const int tid = threadIdx.x, lane = tid & 63, wid = tid >> 6;
    const int waveId = blockIdx.x * 4 + wid;
    const int nWaves = gridDim.x * 4;
    const int total = *novercnt * 128;
    for (int w = waveId; w < total; w += nWaves) {
        const int oi = w >> 7;
        const int chunk = w & 127;
        const int r = worklist[oi];
        const int col = chunk * 64 + lane;
        const float4* xv = reinterpret_cast<const float4*>(X + (size_t)r * DD);
        const float4* cv = reinterpret_cast<const float4*>(CB + (size_t)col * DD);
        float acc = 0.f;
        #pragma unroll 8
        for (int d4 = 0; d4 < 64; ++d4) {
            float4 a = xv[d4], b = cv[d4];
            acc = fmaf(a.x, b.x, acc);
            acc = fmaf(a.y, b.y, acc);
            acc = fmaf(a.z, b.z, acc);
            acc = fmaf(a.w, b.w, acc);
        }
        float t1 = x2[r] + c2[col];
        float best = t1 - 2.0f * acc;
        int besti = col;
        #pragma unroll
        for (int m = 32; m > 0; m >>= 1) {
            float b2 = __shfl_xor(best, m, 64);
            int   i2 = __shfl_xor(besti, m, 64);
            if (b2 < best || (b2 == best && i2 < besti)) { best = b2; besti = i2; }
        }
        if (lane == 0) {
            unsigned long long packed =
                ((unsigned long long)__float_as_uint(best) << 32) | (unsigned)besti;
            atomicMin(&packedbest[oi], packed);
        }
    }
}

// ---------------------------------------------------------------------------
// Kernel 2e: unpack overflow results -> ids + histogram (once per row).
// ---------------------------------------------------------------------------
__global__ __launch_bounds__(256) void vq_unpack(const int* __restrict__ novercnt,
                                                 const int* __restrict__ worklist,
                                                 const unsigned long long* __restrict__ packedbest,
                                                 const float* __restrict__ mask,
                                                 float* __restrict__ out,
                                                 float* __restrict__ hist) {
    const int i = blockIdx.x * 256 + threadIdx.x;
    if (i < *novercnt) {
        const int r = worklist[i];
        const int besti = (int)(packedbest[i] & 0xFFFFFFFFull);
        out[OUT_IDS + r] = (float)besti;
        atomicAdd(&hist[besti], mask[r]);
    }
}

// ---------------------------------------------------------------------------
// Kernel 3: gather + MSE partials. VERBATIM the verified R0 epilogue ->
//   partial[512] and outq/outst bit-identical. Overwrites ALL scratch.
// ---------------------------------------------------------------------------
__global__ __launch_bounds__(256) void vq_gather(const float* __restrict__ X,
                                                 const float* __restrict__ CB,
                                                 float* __restrict__ out,
                                                 float* __restrict__ partial) {
    __shared__ int   row_id[32];
    __shared__ float wsum[4];
    const int tid  = threadIdx.x;
    const int lane = tid & 63;
    const int wid  = tid >> 6;
    const int block_row = blockIdx.x * 32;

    if (tid < 32) row_id[tid] = (int)out[OUT_IDS + block_row + tid];
    __syncthreads();

    float msep = 0.0f;
    float* outq  = out + OUT_Q;
    float* outst = out + OUT_ST;
    #pragma unroll
    for (int i = 0; i < 8; ++i) {
        int g2 = i * 256 + tid;         // 0..2047 covers 32 rows x 64 float4
        int row = g2 >> 6;
        int d4  = g2 & 63;
        int id  = row_id[row];
        float4 q = reinterpret_cast<const float4*>(CB)[(size_t)id * (DD / 4) + d4];
        float4 x = reinterpret_cast<const float4*>(X)[(size_t)(block_row + row) * (DD / 4) + d4];
        float4 st;
        st.x = x.x + (q.x - x.x);
        st.y = x.y + (q.y - x.y);
        st.z = x.z + (q.z - x.z);
        st.w = x.w + (q.w - x.w);
        float dx = x.x - q.x; msep = fmaf(dx, dx, msep);
        dx = x.y - q.y; msep = fmaf(dx, dx, msep);
        dx = x.z - q.z; msep = fmaf(dx, dx, msep);
        dx = x.w - q.w; msep = fmaf(dx, dx, msep);
        size_t o = (size_t)(block_row + row) * (DD / 4) + d4;
        reinterpret_cast<float4*>(outq)[o]  = q;
        reinterpret_cast<float4*>(outst)[o] = st;
    }
    #pragma unroll
    for (int off = 32; off > 0; off >>= 1) msep += __shfl_down(msep, off, 64);
    if (lane == 0) wsum[wid] = msep;
    __syncthreads();
    if (tid == 0) partial[blockIdx.x] = wsum[0] + wsum[1] + wsum[2] + wsum[3];
}

// ---------------------------------------------------------------------------
// Kernel 4: finalize losses + perplexity (double precision, single block)
// ---------------------------------------------------------------------------
__global__ __launch_bounds__(256) void vq_finalize(const float* __restrict__ partial,
                                                   const float* __restrict__ hist,
                                                   float* __restrict__ out) {
    __shared__ double red[256];
    const int tid = threadIdx.x;

    double ps = 0.0;
    for (int j = tid; j < NBLOCKS; j += 256) ps += (double)partial[j];
    red[tid] = ps;
    __syncthreads();
    for (int s = 128; s > 0; s >>= 1) {
        if (tid < s) red[tid] += red[tid + s];
        __syncthreads();
    }
    double mse_sum = red[0];
    __syncthreads();

    double hs = 0.0;
    for (int j = tid; j < KK; j += 256) hs += (double)hist[j];
    red[tid] = hs;
    __syncthreads();
    for (int s = 128; s > 0; s >>= 1) {
        if (tid < s) red[tid] += red[tid + s];
        __syncthreads();
    }
    double denom = red[0] > 1.0 ? red[0] : 1.0;
    __syncthreads();

    double ent = 0.0;
    for (int j = tid; j < KK; j += 256) {
        double p = (double)hist[j] / denom;
        ent += p * log(p + 1e-8);
    }
    red[tid] = ent;
    __syncthreads();
    for (int s = 128; s > 0; s >>= 1) {
        if (tid < s) red[tid] += red[tid + s];
        __syncthreads();
    }

    if (tid == 0) {
        double mse = mse_sum / (double)((size_t)NN * DD);
        out[OUT_COMMIT] = (float)(mse * 0.25);
        out[OUT_CBL]    = (float)mse;
        out[OUT_PERP]   = (float)exp(-red[0]);
    }
}

// ---------------------------------------------------------------------------
extern "C" void kernel_launch(void* const* d_in, const int* in_sizes, int n_in,
                              void* d_out, int out_size, void* d_ws, size_t ws_size,
                              hipStream_t stream) {
    const float* latents = (const float*)d_in[0];   // [16,1024,256]
    const float* mask    = (const float*)d_in[1];   // [16,1024]
    const float* cb      = (const float*)d_in[2];   // [8192,256]
    float* out = (float*)d_out;

    // workspace (floats): hist[8192] | partial[512] | c2[8192] | x2[16384]
    float* hist    = (float*)d_ws;
    float* partial = hist + KK;
    float* c2      = partial + NBLOCKS;
    float* x2      = c2 + KK;

    // scratch in the out buffer, all fully overwritten by vq_gather:
    //   OUT_Q region : Xb bf16[NN][DD] + CBb bf16[KK][DD]
    //   OUT_ST region: candlist int[NN][128] | candcnt[NN] | amin2[NN][2] |
    //                  flag | novercnt | worklist[NN] | packedbest u64[NN]
    unsigned short* Xb  = (unsigned short*)(out + OUT_Q);
    unsigned short* CBb = (unsigned short*)(out + OUT_Q + 2097152);
    int*   candlist = (int*)(out + OUT_ST);
    int*   candcnt  = candlist + (size_t)NN * CANDCAP;
    float* amin2    = (float*)(candcnt + NN);
    int*   flag     = (int*)(amin2 + 2 * NN);
    int*   novercnt = flag + 1;
    int*   worklist = novercnt + 1;
    unsigned long long* packedbest =
        (unsigned long long*)(worklist + NN);   // float-offset even -> 8B aligned

    hipMemsetAsync(hist, 0, KK * sizeof(float), stream);          // zero histogram
    hipMemsetAsync(candcnt, 0, NN * sizeof(int), stream);         // zero cand counts
    hipMemsetAsync(novercnt, 0, sizeof(int), stream);             // zero overflow cnt
    hipMemsetAsync(packedbest, 0xFF, NN * 8, stream);             // +inf packed best
    rowsumsq<<<KK / 64, 256, 0, stream>>>(cb, c2);                 // numpy-exact |c|^2
    rowsumsq<<<NN / 64, 256, 0, stream>>>(latents, x2);            // numpy-exact |x|^2
    f2bf4<<<(NN * DD / 4) / 256, 256, 0, stream>>>(
        (const float4*)latents, (ushort4*)Xb);
    f2bf4<<<(KK * DD / 4) / 256, 256, 0, stream>>>(
        (const float4*)cb, (ushort4*)CBb);
    mfma_check<<<1, 64, 0, stream>>>(flag);
    mfma_minpass<<<512, 256, 0, stream>>>(Xb, CBb, c2, x2, amin2, flag);
    mfma_candpass<<<512, 256, 0, stream>>>(Xb, CBb, c2, x2, amin2,
                                           candcnt, candlist, flag);
    rescore<<<NN / 4, 256, 0, stream>>>(latents, cb, c2, x2, mask,
                                        candcnt, candlist, flag,
                                        novercnt, worklist, out, hist);
    vq_overflow<<<2048, 256, 0, stream>>>(latents, cb, c2, x2,
                                          novercnt, worklist, packedbest);
    vq_unpack<<<NN / 256, 256, 0, stream>>>(novercnt, worklist, packedbest,
                                            mask, out, hist);
    vq_gather<<<NBLOCKS, 256, 0, stream>>>(latents, cb, out, partial);
    vq_finalize<<<1, 256, 0, stream>>>(partial, hist, out);
}